// Round 3
// baseline (326.658 us; speedup 1.0000x reference)
//
#include <hip/hip_runtime.h>

// OptPosEncVol: trilinear interpolation of a dense 64^3 x 64ch fp32 grid.
// coords: [8, 65536, 3] fp32 in [0,1); shape_code: [64, 262144] fp32;
// out: [8, 65536, 64] fp32.
//
// R3 design: coords occupy only [31.5,63)^3 -> active corner set ~9.2MB with
// ~117x reuse per corner row. Random point order wastes it (R2: FETCH=314MB,
// 103us). Fix: counting-sort points by cell id, then gather in sorted order
// so consecutive waves hit the same L2 lines.
//   1. transpose_k:  [C][T] -> ws.tt [T][C]          (corner rows contiguous)
//   2. memset hist=0; hist_k: histogram of cell ids   (262144 bins)
//   3. scan_a/scan_b: 2-level exclusive scan of hist -> base, aux
//   4. scatter_k: sorted[pos] = (sx,sy,sz,pid)        (pos via base+atomicSub)
//   5. interp_sorted_k: 4 points/wave, 8 coalesced float4 corner gathers
//      (now L2-local), scattered 256B output stores.

#define CODE_NUM 64
#define CODE_CHANNEL 64
#define TABLE (CODE_NUM * CODE_NUM * CODE_NUM)  // 262144
#define NCELLS TABLE                            // cell id == base corner index

typedef unsigned int uint;

__global__ __launch_bounds__(256) void transpose_k(const float* __restrict__ src,
                                                   float* __restrict__ dst) {
    __shared__ float tile[64 * 65];
    const int t0 = blockIdx.x * 64;
    const int j = threadIdx.x;
#pragma unroll
    for (int i = 0; i < 4; ++i) {
        const int q = (i << 8) | j;
        const int c = q >> 4;
        const int tc4 = q & 15;
        const float4 v = *(const float4*)(src + (size_t)c * TABLE + t0 + (tc4 << 2));
        tile[((tc4 << 2) + 0) * 65 + c] = v.x;
        tile[((tc4 << 2) + 1) * 65 + c] = v.y;
        tile[((tc4 << 2) + 2) * 65 + c] = v.z;
        tile[((tc4 << 2) + 3) * 65 + c] = v.w;
    }
    __syncthreads();
#pragma unroll
    for (int i = 0; i < 4; ++i) {
        const int q = (i << 8) | j;
        const int t = q >> 4;
        const int c4 = q & 15;
        float4 v;
        v.x = tile[t * 65 + (c4 << 2) + 0];
        v.y = tile[t * 65 + (c4 << 2) + 1];
        v.z = tile[t * 65 + (c4 << 2) + 2];
        v.w = tile[t * 65 + (c4 << 2) + 3];
        *(float4*)(dst + (size_t)(t0 + t) * 64 + (c4 << 2)) = v;
    }
}

__device__ __forceinline__ int cell_of(const float* coords, int p,
                                       float& sx, float& sy, float& sz) {
    sx = (coords[p * 3 + 0] + 1.0f) * ((CODE_NUM - 1) * 0.5f);
    sy = (coords[p * 3 + 1] + 1.0f) * ((CODE_NUM - 1) * 0.5f);
    sz = (coords[p * 3 + 2] + 1.0f) * ((CODE_NUM - 1) * 0.5f);
    const int ix = (int)floorf(sx), iy = (int)floorf(sy), iz = (int)floorf(sz);
    return ix + iy * CODE_NUM + iz * (CODE_NUM * CODE_NUM);
}

__global__ __launch_bounds__(256) void hist_k(const float* __restrict__ coords,
                                              uint* __restrict__ hist, int npoints) {
    const int p = blockIdx.x * 256 + threadIdx.x;
    if (p >= npoints) return;
    float sx, sy, sz;
    const int cell = cell_of(coords, p, sx, sy, sz);
    atomicAdd(&hist[cell], 1u);
}

// 256 blocks x 256 threads, 4 bins/thread: per-chunk exclusive scan -> base,
// chunk totals -> aux[256].
__global__ __launch_bounds__(256) void scan_a(const uint* __restrict__ hist,
                                              uint* __restrict__ base,
                                              uint* __restrict__ aux) {
    __shared__ uint s[256];
    const int b = blockIdx.x, t = threadIdx.x;
    const uint4 h = ((const uint4*)hist)[b * 256 + t];
    const uint sum = h.x + h.y + h.z + h.w;
    s[t] = sum;
    __syncthreads();
    for (int off = 1; off < 256; off <<= 1) {
        const uint v = (t >= off) ? s[t - off] : 0u;
        __syncthreads();
        s[t] += v;
        __syncthreads();
    }
    const uint incl = s[t];
    const uint excl = incl - sum;
    uint4 e;
    e.x = excl; e.y = excl + h.x; e.z = e.y + h.y; e.w = e.z + h.z;
    ((uint4*)base)[b * 256 + t] = e;
    if (t == 255) aux[b] = incl;
}

// 1 block: exclusive scan of aux[256] in place.
__global__ __launch_bounds__(256) void scan_b(uint* __restrict__ aux) {
    __shared__ uint s[256];
    const int t = threadIdx.x;
    const uint v = aux[t];
    s[t] = v;
    __syncthreads();
    for (int off = 1; off < 256; off <<= 1) {
        const uint u = (t >= off) ? s[t - off] : 0u;
        __syncthreads();
        s[t] += u;
        __syncthreads();
    }
    aux[t] = s[t] - v;  // exclusive
}

__global__ __launch_bounds__(256) void scatter_k(const float* __restrict__ coords,
                                                 uint* __restrict__ hist,
                                                 const uint* __restrict__ base,
                                                 const uint* __restrict__ aux,
                                                 float4* __restrict__ sorted,
                                                 int npoints) {
    const int p = blockIdx.x * 256 + threadIdx.x;
    if (p >= npoints) return;
    float sx, sy, sz;
    const int cell = cell_of(coords, p, sx, sy, sz);
    const uint start = base[cell] + aux[cell >> 10];
    const uint r = atomicSub(&hist[cell], 1u) - 1u;  // intra-cell rank (any order ok)
    sorted[start + r] = make_float4(sx, sy, sz, __int_as_float(p));
}

// 4 points per wave; lane l -> point l>>4, channels 4*(l&15)..+3.
__global__ __launch_bounds__(256) void interp_sorted_k(const float4* __restrict__ sorted,
                                                       const float* __restrict__ table,
                                                       const int* __restrict__ idxp,
                                                       float* __restrict__ out,
                                                       int npoints) {
    const unsigned tid = blockIdx.x * 256u + threadIdx.x;
    const int lane = threadIdx.x & 63;
    const int sub = lane >> 4;
    const int cg = lane & 15;
    const int j = (int)((tid >> 6) * 4u + (unsigned)sub);
    if (j >= npoints) return;

    const float4 f = sorted[j];  // 16 lanes broadcast the same 16B
    const float sx = f.x, sy = f.y, sz = f.z;
    const int p = __float_as_int(f.w);

    const int offset = idxp[0] * TABLE;
    const float fx = floorf(sx), fy = floorf(sy), fz = floorf(sz);
    const float rx = sx - fx, ry = sy - fy, rz = sz - fz;
    const int base = offset + (int)fx + (int)fy * CODE_NUM + (int)fz * (CODE_NUM * CODE_NUM);

    const float wx[2] = {1.0f - rx, rx};
    const float wy[2] = {1.0f - ry, ry};
    const float wz[2] = {1.0f - rz, rz};

    const char* tp = (const char*)table;
    const int cgoff = cg << 4;

    float4 acc = make_float4(0.f, 0.f, 0.f, 0.f);
#pragma unroll
    for (int k = 0; k < 8; ++k) {
        const int a = k & 1, b = (k >> 1) & 1, c = (k >> 2) & 1;
        const int idx = base + a + b * CODE_NUM + c * (CODE_NUM * CODE_NUM);
        const float w = wx[a] * wy[b] * wz[c];
        const float4 v = *(const float4*)(tp + ((size_t)(unsigned)(idx << 8) + cgoff));
        acc.x = fmaf(w, v.x, acc.x);
        acc.y = fmaf(w, v.y, acc.y);
        acc.z = fmaf(w, v.z, acc.z);
        acc.w = fmaf(w, v.w, acc.w);
    }
    *(float4*)(out + (size_t)p * CODE_CHANNEL + (cg << 2)) = acc;  // 256B/point
}

// ---- fallbacks (smaller workspace) ----
__global__ __launch_bounds__(256) void interp4_k(const float* __restrict__ coords,
                                                 const float* __restrict__ table,
                                                 const int* __restrict__ idxp,
                                                 float* __restrict__ out,
                                                 int npoints) {
    const unsigned tid = blockIdx.x * 256u + threadIdx.x;
    const int lane = threadIdx.x & 63;
    const int sub = lane >> 4;
    const int cg = lane & 15;
    const int p = (int)((tid >> 6) * 4u + (unsigned)sub);
    if (p >= npoints) return;
    const int offset = idxp[0] * TABLE;
    float sx, sy, sz;
    const int cell = cell_of(coords, p, sx, sy, sz);
    const float rx = sx - floorf(sx), ry = sy - floorf(sy), rz = sz - floorf(sz);
    const int base = offset + cell;
    const float wx[2] = {1.0f - rx, rx};
    const float wy[2] = {1.0f - ry, ry};
    const float wz[2] = {1.0f - rz, rz};
    const char* tp = (const char*)table;
    const int cgoff = cg << 4;
    float4 acc = make_float4(0.f, 0.f, 0.f, 0.f);
#pragma unroll
    for (int k = 0; k < 8; ++k) {
        const int a = k & 1, b = (k >> 1) & 1, c = (k >> 2) & 1;
        const int idx = base + a + b * CODE_NUM + c * (CODE_NUM * CODE_NUM);
        const float w = wx[a] * wy[b] * wz[c];
        const float4 v = *(const float4*)(tp + ((size_t)(unsigned)(idx << 8) + cgoff));
        acc.x = fmaf(w, v.x, acc.x);
        acc.y = fmaf(w, v.y, acc.y);
        acc.z = fmaf(w, v.z, acc.z);
        acc.w = fmaf(w, v.w, acc.w);
    }
    *(float4*)(out + (size_t)p * CODE_CHANNEL + (cg << 2)) = acc;
}

__global__ __launch_bounds__(256) void interp_fallback_k(const float* __restrict__ coords,
                                                         const float* __restrict__ table,
                                                         const int* __restrict__ idxp,
                                                         float* __restrict__ out,
                                                         int npoints) {
    const int p = (int)((blockIdx.x * 256u + threadIdx.x) >> 6);
    const int lane = threadIdx.x & 63;
    if (p >= npoints) return;
    const int offset = idxp[0] * TABLE;
    float sx, sy, sz;
    const int cell = cell_of(coords, p, sx, sy, sz);
    const float rx = sx - floorf(sx), ry = sy - floorf(sy), rz = sz - floorf(sz);
    const int base = offset + cell;
    const float wx[2] = {1.0f - rx, rx};
    const float wy[2] = {1.0f - ry, ry};
    const float wz[2] = {1.0f - rz, rz};
    float acc = 0.0f;
#pragma unroll
    for (int k = 0; k < 8; ++k) {
        const int a = k & 1, b = (k >> 1) & 1, c = (k >> 2) & 1;
        const int idx = base + a + b * CODE_NUM + c * (CODE_NUM * CODE_NUM);
        acc = fmaf(wx[a] * wy[b] * wz[c], table[(size_t)lane * TABLE + idx], acc);
    }
    out[(size_t)p * CODE_CHANNEL + lane] = acc;
}

extern "C" void kernel_launch(void* const* d_in, const int* in_sizes, int n_in,
                              void* d_out, int out_size, void* d_ws, size_t ws_size,
                              hipStream_t stream) {
    const float* coords = (const float*)d_in[0];
    const float* code   = (const float*)d_in[1];
    const int*   idxp   = (const int*)d_in[2];
    float* out = (float*)d_out;

    const int npoints = in_sizes[0] / 3;  // 524288
    const size_t MB = 1024ull * 1024ull;
    const size_t tbytes = (size_t)TABLE * CODE_CHANNEL * sizeof(float);  // 64 MB

    // ws layout: tt 64MB | sorted 8MB | hist 1MB | base 1MB | aux 4KB
    const size_t off_sorted = tbytes;
    const size_t off_hist = off_sorted + (size_t)npoints * 16;
    const size_t off_base = off_hist + (size_t)NCELLS * 4;
    const size_t off_aux  = off_base + (size_t)NCELLS * 4;
    const size_t need = off_aux + 4096;

    char* ws = (char*)d_ws;
    const int pblocks = (npoints + 255) / 256;

    if (ws_size >= need) {
        float*  tt     = (float*)(ws);
        float4* sorted = (float4*)(ws + off_sorted);
        uint*   hist   = (uint*)(ws + off_hist);
        uint*   basep  = (uint*)(ws + off_base);
        uint*   aux    = (uint*)(ws + off_aux);

        hipMemsetAsync(hist, 0, (size_t)NCELLS * 4, stream);
        transpose_k<<<TABLE / 64, 256, 0, stream>>>(code, tt);
        hist_k<<<pblocks, 256, 0, stream>>>(coords, hist, npoints);
        scan_a<<<256, 256, 0, stream>>>(hist, basep, aux);
        scan_b<<<1, 256, 0, stream>>>(aux);
        scatter_k<<<pblocks, 256, 0, stream>>>(coords, hist, basep, aux, sorted, npoints);
        interp_sorted_k<<<(npoints + 15) / 16, 256, 0, stream>>>(sorted, tt, idxp, out, npoints);
    } else if (ws_size >= tbytes) {
        float* tt = (float*)ws;
        transpose_k<<<TABLE / 64, 256, 0, stream>>>(code, tt);
        interp4_k<<<(npoints + 15) / 16, 256, 0, stream>>>(coords, tt, idxp, out, npoints);
    } else {
        interp_fallback_k<<<(npoints + 3) / 4, 256, 0, stream>>>(coords, code, idxp, out, npoints);
    }
}